// Round 12
// baseline (365.949 us; speedup 1.0000x reference)
//
#include <hip/hip_runtime.h>

#define NNODES 50000
#define NEDGES 800000
#define NCLASS 40
#define NBLK_SCAN 196   // ceil(50000/256)
#define CNTB  3125      // NEDGES/256
#define PREPB 320       // 5*16384/256
#define WOUTB 24        // 48*128/256
#define GEMMB 782       // ceil(NNODES/64)
#define ATTNB 1564      // ceil(50000/128)*4 layers

typedef _Float16 half8  __attribute__((ext_vector_type(8)));
typedef _Float16 half4  __attribute__((ext_vector_type(4)));
typedef float    floatx4 __attribute__((ext_vector_type(4)));

// LDS weight tile: 128 rows x 136 halfs (272B stride -> 2-way bank aliasing, free)
#define WSTRIDE 136
#define SMEM_BYTES (128 * WSTRIDE * 2)   // 34,816 B >= Cs 64*132*4 = 33,792 B

__device__ __forceinline__ float fast_tanh(float x) {
    return 1.0f - 2.0f / (__expf(2.0f * x) + 1.0f);
}

__device__ __forceinline__ void stage_weight(const _Float16* __restrict__ WT, _Float16* Wsh, int tid) {
#pragma unroll
    for (int it = 0; it < 8; ++it) {
        int idx = it * 256 + tid;            // 2048 chunks of 8 halfs
        int n = idx >> 4, k8 = (idx & 15) * 8;
        *(half8*)&Wsh[n * WSTRIDE + k8] = *(const half8*)(WT + n * 128 + k8);
    }
}

// ---------------- fused pre-pass: count+rank | prepw | prep WoutT ----------------
__global__ __launch_bounds__(256) void k_pre(const int* __restrict__ dst, int* __restrict__ cnt,
                                             int* __restrict__ rank,
                                             const float* __restrict__ convW, const float* __restrict__ W_att,
                                             _Float16* __restrict__ WT,
                                             const float* __restrict__ Wout, _Float16* __restrict__ WoutT) {
    int bid = blockIdx.x, tid = threadIdx.x;
    if (bid < CNTB) {
        int e = bid * 256 + tid;
        rank[e] = atomicAdd(&cnt[dst[e]], 1);
    } else if (bid < CNTB + PREPB) {
        int idx = (bid - CNTB) * 256 + tid;   // < 5*16384
        int mat = idx >> 14, rem = idx & 16383;
        int n = rem >> 7, k = rem & 127;
        const float* src = (mat < 4) ? (convW + mat * 16384) : W_att;
        WT[idx] = (_Float16)src[k * 128 + n];
    } else {
        int idx = (bid - CNTB - PREPB) * 256 + tid;   // < 48*128
        int j = idx >> 7, c = idx & 127;
        WoutT[idx] = (j < NCLASS) ? (_Float16)Wout[c * NCLASS + j] : (_Float16)0.f;
    }
}

__global__ __launch_bounds__(256) void k_bsum(const int* __restrict__ cnt, int* __restrict__ bsum) {
    int t = threadIdx.x, b = blockIdx.x;
    int i = b * 256 + t;
    int c = (i < NNODES) ? cnt[i] : 0;
    int v = c;
    v += __shfl_xor(v, 1);  v += __shfl_xor(v, 2);  v += __shfl_xor(v, 4);
    v += __shfl_xor(v, 8);  v += __shfl_xor(v, 16); v += __shfl_xor(v, 32);
    __shared__ int ws[4];
    if ((t & 63) == 0) ws[t >> 6] = v;
    __syncthreads();
    if (t == 0) bsum[b] = ws[0] + ws[1] + ws[2] + ws[3];
}

__global__ __launch_bounds__(256) void k_offsets(const int* __restrict__ cnt, const int* __restrict__ bsum,
                                                 int* __restrict__ offsets, float* __restrict__ dinv) {
    int t = threadIdx.x, b = blockIdx.x;
    int i = b * 256 + t;
    int c = (i < NNODES) ? cnt[i] : 0;
    int pv = (t < b) ? bsum[t] : 0;   // b <= 195 < 256
    int rv = pv;
    rv += __shfl_xor(rv, 1);  rv += __shfl_xor(rv, 2);  rv += __shfl_xor(rv, 4);
    rv += __shfl_xor(rv, 8);  rv += __shfl_xor(rv, 16); rv += __shfl_xor(rv, 32);
    __shared__ int wsum[4];
    __shared__ int part[256];
    if ((t & 63) == 0) wsum[t >> 6] = rv;
    part[t] = c;
    __syncthreads();
    int boff = wsum[0] + wsum[1] + wsum[2] + wsum[3];
#pragma unroll
    for (int d = 1; d < 256; d <<= 1) {
        int v = (t >= d) ? part[t - d] : 0;
        __syncthreads();
        part[t] += v;
        __syncthreads();
    }
    if (i < NNODES) {
        offsets[i] = boff + part[t] - c;
        dinv[i] = rsqrtf((float)c + 1.0f);
    }
    if (b == 0 && t == 0) offsets[NNODES] = NEDGES;
}

// ---------------- shared GEMM body: C[64,128] tile = (A @ W) * dinv; W staged in LDS ----------------
// smem serves as W-tile (34.8 KB) during MFMA, then is REUSED as the fp32 Cs epilogue buffer.
// F32A: A is fp32 (layer 0 reads x directly, converts in-register -- identical rounding to a f2h pass).
template <bool F32A>
__device__ __forceinline__ void gemm_body(const void* __restrict__ Av, const _Float16* __restrict__ WT,
                                          const float* __restrict__ dinv, _Float16* __restrict__ C,
                                          int m0, char* smem) {
    _Float16* Wsh = (_Float16*)smem;
    float (*Cs)[132] = (float (*)[132])smem;
    int tid = threadIdx.x;
    int wave = tid >> 6, lane = tid & 63;
    int quad = lane >> 4, l15 = lane & 15;
    int ko = quad * 8;

    stage_weight(WT, Wsh, tid);
    __syncthreads();

    floatx4 acc[4][2];
#pragma unroll
    for (int rt = 0; rt < 4; ++rt)
#pragma unroll
        for (int ct = 0; ct < 2; ++ct) acc[rt][ct] = (floatx4){0.f, 0.f, 0.f, 0.f};

#pragma unroll
    for (int kk = 0; kk < 4; ++kk) {
        half8 a[4], b[2];
#pragma unroll
        for (int rt = 0; rt < 4; ++rt) {
            int row = m0 + rt * 16 + l15;
            if (row > NNODES - 1) row = NNODES - 1;
            if (F32A) {
                const float* Ap = (const float*)Av + (size_t)row * 128 + kk * 32 + ko;
                float4 f0 = *(const float4*)Ap;
                float4 f1 = *(const float4*)(Ap + 4);
                a[rt] = (half8){(_Float16)f0.x, (_Float16)f0.y, (_Float16)f0.z, (_Float16)f0.w,
                                (_Float16)f1.x, (_Float16)f1.y, (_Float16)f1.z, (_Float16)f1.w};
            } else {
                a[rt] = *(const half8*)((const _Float16*)Av + (size_t)row * 128 + kk * 32 + ko);
            }
        }
#pragma unroll
        for (int ct = 0; ct < 2; ++ct) {
            int n = wave * 32 + ct * 16 + l15;
            b[ct] = *(const half8*)&Wsh[n * WSTRIDE + kk * 32 + ko];
        }
#pragma unroll
        for (int rt = 0; rt < 4; ++rt)
#pragma unroll
            for (int ct = 0; ct < 2; ++ct)
                acc[rt][ct] = __builtin_amdgcn_mfma_f32_16x16x32_f16(a[rt], b[ct], acc[rt][ct], 0, 0, 0);
    }
    __syncthreads();   // all waves done reading Wsh before Cs overwrites it

#pragma unroll
    for (int rt = 0; rt < 4; ++rt)
#pragma unroll
        for (int ct = 0; ct < 2; ++ct)
#pragma unroll
            for (int r = 0; r < 4; ++r)
                Cs[rt * 16 + quad * 4 + r][wave * 32 + ct * 16 + l15] = acc[rt][ct][r];
    __syncthreads();
    int row = tid >> 2, seg = tid & 3;
    int gm = m0 + row;
    if (gm < NNODES) {
        float sc = dinv[gm];
#pragma unroll
        for (int j = 0; j < 4; ++j) {
            float4 f0 = *(const float4*)&Cs[row][seg * 32 + j * 8];
            float4 f1 = *(const float4*)&Cs[row][seg * 32 + j * 8 + 4];
            half8 o = {(_Float16)(f0.x * sc), (_Float16)(f0.y * sc), (_Float16)(f0.z * sc), (_Float16)(f0.w * sc),
                       (_Float16)(f1.x * sc), (_Float16)(f1.y * sc), (_Float16)(f1.z * sc), (_Float16)(f1.w * sc)};
            *(half8*)(C + (size_t)gm * 128 + seg * 32 + j * 8) = o;
        }
    }
}

__global__ __launch_bounds__(256) void k_gemm_f16(const _Float16* __restrict__ A, const _Float16* __restrict__ WT,
                                                  const float* __restrict__ dinv, _Float16* __restrict__ C) {
    __shared__ __align__(16) char smem[SMEM_BYTES];
    gemm_body<false>(A, WT, dinv, C, blockIdx.x * 64, smem);
}

// ---------------- fused: CSR fill (no atomic) | layer-0 GEMM straight from fp32 x ----------------
__global__ __launch_bounds__(256) void k_fillgemm(const int* __restrict__ src, const int* __restrict__ dst,
                                                  const int* __restrict__ offsets, const int* __restrict__ rank,
                                                  int* __restrict__ esrc,
                                                  const float* __restrict__ x, const _Float16* __restrict__ WT,
                                                  const float* __restrict__ dinv, _Float16* __restrict__ C) {
    __shared__ __align__(16) char smem[SMEM_BYTES];
    int bid = blockIdx.x;
    if (bid < GEMMB) {
        gemm_body<true>(x, WT, dinv, C, bid * 64, smem);
    } else {
        int e = (bid - GEMMB) * 256 + threadIdx.x;
        int d = dst[e];
        esrc[offsets[d] + rank[e]] = src[e];
    }
}

// ---------------- edge aggregation: quarter-wave rows, fully predicated 8-wide gather windows ----------
__global__ __launch_bounds__(256) void k_aggregate(const _Float16* __restrict__ hWs, const int* __restrict__ offsets,
                                                   const int* __restrict__ esrc, const float* __restrict__ dinv,
                                                   const float* __restrict__ bias, _Float16* __restrict__ outh) {
    __shared__ float bsh[128];
    int tid = threadIdx.x;
    if (tid < 128) bsh[tid] = bias[tid];
    __syncthreads();
    int lane = tid & 63, wave = tid >> 6;
    int half = lane >> 5;
    int q = (lane >> 4) & 1;
    int l16 = lane & 15;
    int c8 = l16 * 8;
    int n = blockIdx.x * 8 + wave * 2 + half;
    int beg = offsets[n], end = offsets[n + 1];
    float a0 = 0.f, a1 = 0.f, a2 = 0.f, a3 = 0.f, a4 = 0.f, a5 = 0.f, a6 = 0.f, a7 = 0.f;
    for (int e = beg + q; e < end; e += 16) {
        int  idx[8];
        float msk[8];
#pragma unroll
        for (int i = 0; i < 8; ++i) {
            int ei = e + 2 * i;
            int t = esrc[ei];            // esrc padded: speculative load in-bounds
            bool ok = ei < end;
            idx[i] = ok ? t : n;
            msk[i] = ok ? 1.f : 0.f;
        }
        half8 v[8];
#pragma unroll
        for (int i = 0; i < 8; ++i) v[i] = *(const half8*)(hWs + (size_t)idx[i] * 128 + c8);
#pragma unroll
        for (int i = 0; i < 8; ++i) {
            a0 += msk[i] * (float)v[i][0]; a1 += msk[i] * (float)v[i][1];
            a2 += msk[i] * (float)v[i][2]; a3 += msk[i] * (float)v[i][3];
            a4 += msk[i] * (float)v[i][4]; a5 += msk[i] * (float)v[i][5];
            a6 += msk[i] * (float)v[i][6]; a7 += msk[i] * (float)v[i][7];
        }
    }
    a0 += __shfl_xor(a0, 16); a1 += __shfl_xor(a1, 16); a2 += __shfl_xor(a2, 16); a3 += __shfl_xor(a3, 16);
    a4 += __shfl_xor(a4, 16); a5 += __shfl_xor(a5, 16); a6 += __shfl_xor(a6, 16); a7 += __shfl_xor(a7, 16);
    if (q == 0) {
        float dn = dinv[n];
        half8 sv = *(const half8*)(hWs + (size_t)n * 128 + c8);
        float4 b0 = *(const float4*)&bsh[c8];
        float4 b1 = *(const float4*)&bsh[c8 + 4];
        float r0 = (a0 + (float)sv[0]) * dn + b0.x;
        float r1 = (a1 + (float)sv[1]) * dn + b0.y;
        float r2 = (a2 + (float)sv[2]) * dn + b0.z;
        float r3 = (a3 + (float)sv[3]) * dn + b0.w;
        float r4 = (a4 + (float)sv[4]) * dn + b1.x;
        float r5 = (a5 + (float)sv[5]) * dn + b1.y;
        float r6 = (a6 + (float)sv[6]) * dn + b1.z;
        float r7 = (a7 + (float)sv[7]) * dn + b1.w;
        half8 o = {(_Float16)fmaxf(r0, 0.f), (_Float16)fmaxf(r1, 0.f),
                   (_Float16)fmaxf(r2, 0.f), (_Float16)fmaxf(r3, 0.f),
                   (_Float16)fmaxf(r4, 0.f), (_Float16)fmaxf(r5, 0.f),
                   (_Float16)fmaxf(r6, 0.f), (_Float16)fmaxf(r7, 0.f)};
        *(half8*)(outh + (size_t)n * 128 + c8) = o;
    }
}

// ---------------- attention scores: wave = 32 nodes x ONE layer; W_att^T staged in LDS ----------------
__global__ __launch_bounds__(256) void k_attn(const _Float16* __restrict__ hbase, const _Float16* __restrict__ WTatt,
                                              const float* __restrict__ a_att, float* __restrict__ scores) {
    __shared__ __align__(16) _Float16 Wsh[128 * WSTRIDE];
    const size_t LSTR = (size_t)NNODES * 128;
    int tid = threadIdx.x;
    int wave = tid >> 6, lane = tid & 63;
    int quad = lane >> 4, l15 = lane & 15;
    int ko = quad * 8;
    int bid = blockIdx.x;
    int layer = bid & 3;
    int nb = (bid >> 2) * 128 + wave * 32;        // 32 nodes per wave, single layer
    const _Float16* hs = hbase + (size_t)layer * LSTR;

    stage_weight(WTatt, Wsh, tid);

    half8 af[2][4];                                // 2 row-tiles of 16 nodes
#pragma unroll
    for (int rt = 0; rt < 2; ++rt) {
        int node = nb + rt * 16 + l15;
        if (node > NNODES - 1) node = NNODES - 1;
        const _Float16* Ap = hs + (size_t)node * 128 + ko;
#pragma unroll
        for (int kk = 0; kk < 4; ++kk) af[rt][kk] = *(const half8*)(Ap + kk * 32);
    }
    __syncthreads();

    float p[2][4];
#pragma unroll
    for (int rt = 0; rt < 2; ++rt)
#pragma unroll
        for (int r = 0; r < 4; ++r) p[rt][r] = 0.f;
#pragma unroll
    for (int ct = 0; ct < 8; ++ct) {
        int ncol = ct * 16 + l15;
        half8 b[4];
#pragma unroll
        for (int kk = 0; kk < 4; ++kk) b[kk] = *(const half8*)&Wsh[ncol * WSTRIDE + kk * 32 + ko];
        floatx4 acc[2];
#pragma unroll
        for (int rt = 0; rt < 2; ++rt) acc[rt] = (floatx4){0.f, 0.f, 0.f, 0.f};
#pragma unroll
        for (int kk = 0; kk < 4; ++kk)
#pragma unroll
            for (int rt = 0; rt < 2; ++rt)
                acc[rt] = __builtin_amdgcn_mfma_f32_16x16x32_f16(af[rt][kk], b[kk], acc[rt], 0, 0, 0);
        float av = a_att[ncol];
#pragma unroll
        for (int rt = 0; rt < 2; ++rt)
#pragma unroll
            for (int r = 0; r < 4; ++r) p[rt][r] += av * fast_tanh(acc[rt][r]);
    }
#pragma unroll
    for (int rt = 0; rt < 2; ++rt)
#pragma unroll
        for (int r = 0; r < 4; ++r) {
            float v = p[rt][r];
            v += __shfl_xor(v, 1); v += __shfl_xor(v, 2);
            v += __shfl_xor(v, 4); v += __shfl_xor(v, 8);
            if (l15 == 0) {
                int nd = nb + rt * 16 + quad * 4 + r;
                if (nd < NNODES) scores[(size_t)nd * 4 + layer] = v;
            }
        }
}

// ---------------- softmax + layer-fuse (coalesced, all lanes) + MFMA out-projection ----------------
__global__ __launch_bounds__(256) void k_fuse_out(const _Float16* __restrict__ hbase, const float* __restrict__ scores,
                                                  const _Float16* __restrict__ WoutT, const float* __restrict__ bout,
                                                  float* __restrict__ out) {
    __shared__ __align__(16) _Float16 Fs[64][136];   // 17,408 B
    __shared__ float salpha[256];
    const size_t LSTR = (size_t)NNODES * 128;
    int tid = threadIdx.x;
    int n0 = blockIdx.x * 64;

    if (tid < 64) {
        int node = n0 + tid; if (node > NNODES - 1) node = NNODES - 1;
        float4 s = *(const float4*)(scores + (size_t)node * 4);
        float mx = fmaxf(fmaxf(s.x, s.y), fmaxf(s.z, s.w));
        float e0 = __expf(s.x - mx), e1 = __expf(s.y - mx), e2 = __expf(s.z - mx), e3 = __expf(s.w - mx);
        float inv = 1.0f / (e0 + e1 + e2 + e3);
        salpha[tid * 4 + 0] = e0 * inv; salpha[tid * 4 + 1] = e1 * inv;
        salpha[tid * 4 + 2] = e2 * inv; salpha[tid * 4 + 3] = e3 * inv;
    }
    __syncthreads();

    // fused = sum_l alpha_l * h_l; all 256 lanes, coalesced per (layer, j)
    {
        int no = tid >> 2, seg = tid & 3;
        int node = n0 + no; if (node > NNODES - 1) node = NNODES - 1;
        float al0 = salpha[no * 4 + 0], al1 = salpha[no * 4 + 1];
        float al2 = salpha[no * 4 + 2], al3 = salpha[no * 4 + 3];
        const _Float16* hp = hbase + (size_t)node * 128 + seg * 32;
#pragma unroll
        for (int j = 0; j < 4; ++j) {
            half8 h0 = *(const half8*)(hp + 0 * LSTR + j * 8);
            half8 h1 = *(const half8*)(hp + 1 * LSTR + j * 8);
            half8 h2 = *(const half8*)(hp + 2 * LSTR + j * 8);
            half8 h3 = *(const half8*)(hp + 3 * LSTR + j * 8);
            half8 f;
#pragma unroll
            for (int u = 0; u < 8; ++u)
                f[u] = (_Float16)(al0 * (float)h0[u] + al1 * (float)h1[u] +
                                  al2 * (float)h2[u] + al3 * (float)h3[u]);
            *(half8*)&Fs[no][seg * 32 + j * 8] = f;
        }
    }
    __syncthreads();

    // out-projection MFMA: 48 padded cols, masked fp32 write + bias
    int wave = tid >> 6, lane = tid & 63;
    int quad = lane >> 4, l15 = lane & 15;
    int ko = quad * 8;
    half8 ff[4];
    int frow = wave * 16 + l15;
#pragma unroll
    for (int kk = 0; kk < 4; ++kk) ff[kk] = *(const half8*)&Fs[frow][kk * 32 + ko];
#pragma unroll
    for (int ct = 0; ct < 3; ++ct) {
        const _Float16* Bp = WoutT + (ct * 16 + l15) * 128 + ko;
        half8 bw[4];
#pragma unroll
        for (int kk = 0; kk < 4; ++kk) bw[kk] = *(const half8*)(Bp + kk * 32);
        floatx4 acc = (floatx4){0.f, 0.f, 0.f, 0.f};
#pragma unroll
        for (int kk = 0; kk < 4; ++kk)
            acc = __builtin_amdgcn_mfma_f32_16x16x32_f16(ff[kk], bw[kk], acc, 0, 0, 0);
        int col = ct * 16 + l15;
        if (col < NCLASS) {
            float bv = bout[col];
#pragma unroll
            for (int r = 0; r < 4; ++r) {
                int node = n0 + wave * 16 + quad * 4 + r;
                if (node < NNODES) out[(size_t)node * NCLASS + col] = acc[r] + bv;
            }
        }
    }
}

extern "C" void kernel_launch(void* const* d_in, const int* in_sizes, int n_in,
                              void* d_out, int out_size, void* d_ws, size_t ws_size,
                              hipStream_t stream) {
    const float* x     = (const float*)d_in[0];
    const int*   ei    = (const int*)d_in[1];
    const float* convW = (const float*)d_in[2];
    const float* convb = (const float*)d_in[3];
    const float* W_att = (const float*)d_in[4];
    const float* a_att = (const float*)d_in[5];
    const float* W_out = (const float*)d_in[6];
    const float* b_out = (const float*)d_in[7];
    float* out = (float*)d_out;

    char* ws = (char*)d_ws;
    size_t off = 0;
    auto take = [&](size_t nbytes) { char* p = ws + off; off += (nbytes + 255) & ~(size_t)255; return p; };
    float*     dinv    = (float*)take(NNODES * 4);
    int*       cnt     = (int*)take(NNODES * 4);
    int*       rank    = (int*)take(NEDGES * 4);
    int*       offsets = (int*)take((NNODES + 1) * 4);
    int*       bsum    = (int*)take(256 * 4);
    int*       esrc    = (int*)take(NEDGES * 4 + 256);   // +64 ints pad for speculative loads
    _Float16*  WoutT   = (_Float16*)take((size_t)48 * 128 * 2);
    float*     scores  = (float*)take(NNODES * 4 * 4);
    _Float16*  WT      = (_Float16*)take((size_t)5 * 128 * 128 * 2);
    _Float16*  hWs     = (_Float16*)take((size_t)NNODES * 128 * 2);
    _Float16*  hh[4];
    for (int l = 0; l < 4; ++l) hh[l] = (_Float16*)take((size_t)NNODES * 128 * 2);
    // NOTE: hh slabs are 12,800,000 B each (multiple of 256) -> contiguous; k_attn/k_fuse_out rely on it.

    const int* src = ei;
    const int* dst = ei + NEDGES;

    hipMemsetAsync(cnt, 0, NNODES * 4, stream);
    k_pre<<<CNTB + PREPB + WOUTB, 256, 0, stream>>>(dst, cnt, rank, convW, W_att, WT, W_out, WoutT);
    k_bsum<<<NBLK_SCAN, 256, 0, stream>>>(cnt, bsum);
    k_offsets<<<NBLK_SCAN, 256, 0, stream>>>(cnt, bsum, offsets, dinv);
    k_fillgemm<<<GEMMB + CNTB, 256, 0, stream>>>(src, dst, offsets, rank, esrc, x, WT, dinv, hWs);

    k_aggregate<<<NNODES / 8, 256, 0, stream>>>(hWs, offsets, esrc, dinv, convb + 0 * 128, hh[0]);
    for (int l = 1; l < 4; ++l) {
        k_gemm_f16<<<GEMMB, 256, 0, stream>>>(hh[l - 1], WT + l * 16384, dinv, hWs);
        k_aggregate<<<NNODES / 8, 256, 0, stream>>>(hWs, offsets, esrc, dinv, convb + l * 128, hh[l]);
    }
    k_attn<<<ATTNB, 256, 0, stream>>>(hh[0], WT + 4 * 16384, a_att, scores);
    k_fuse_out<<<GEMMB, 256, 0, stream>>>(hh[0], scores, WoutT, b_out, out);
}

// Round 13
// 353.971 us; speedup vs baseline: 1.0338x; 1.0338x over previous
//
#include <hip/hip_runtime.h>

#define NNODES 50000
#define NEDGES 800000
#define NCLASS 40
#define NBLK_SCAN 196   // ceil(50000/256)
#define CNTB  3125      // NEDGES/256
#define PREPB 320       // 5*16384/256
#define WOUTB 24        // 48*128/256
#define GEMMB 782       // ceil(NNODES/64)
#define ATTN1B 391      // ceil(50000/128), one layer

typedef _Float16 half8  __attribute__((ext_vector_type(8)));
typedef _Float16 half4  __attribute__((ext_vector_type(4)));
typedef float    floatx4 __attribute__((ext_vector_type(4)));

// LDS weight tile: 128 rows x 136 halfs (272B stride -> 2-way bank aliasing, free)
#define WSTRIDE 136
#define SMEM_BYTES (128 * WSTRIDE * 2)   // 34,816 B >= Cs 64*132*4 = 33,792 B

__device__ __forceinline__ float fast_tanh(float x) {
    return 1.0f - 2.0f / (__expf(2.0f * x) + 1.0f);
}

__device__ __forceinline__ void stage_weight(const _Float16* __restrict__ WT, _Float16* Wsh, int tid) {
#pragma unroll
    for (int it = 0; it < 8; ++it) {
        int idx = it * 256 + tid;            // 2048 chunks of 8 halfs
        int n = idx >> 4, k8 = (idx & 15) * 8;
        *(half8*)&Wsh[n * WSTRIDE + k8] = *(const half8*)(WT + n * 128 + k8);
    }
}

// ---------------- fused pre-pass: count+rank | prepw | prep WoutT ----------------
__global__ __launch_bounds__(256) void k_pre(const int* __restrict__ dst, int* __restrict__ cnt,
                                             int* __restrict__ rank,
                                             const float* __restrict__ convW, const float* __restrict__ W_att,
                                             _Float16* __restrict__ WT,
                                             const float* __restrict__ Wout, _Float16* __restrict__ WoutT) {
    int bid = blockIdx.x, tid = threadIdx.x;
    if (bid < CNTB) {
        int e = bid * 256 + tid;
        rank[e] = atomicAdd(&cnt[dst[e]], 1);
    } else if (bid < CNTB + PREPB) {
        int idx = (bid - CNTB) * 256 + tid;   // < 5*16384
        int mat = idx >> 14, rem = idx & 16383;
        int n = rem >> 7, k = rem & 127;
        const float* src = (mat < 4) ? (convW + mat * 16384) : W_att;
        WT[idx] = (_Float16)src[k * 128 + n];
    } else {
        int idx = (bid - CNTB - PREPB) * 256 + tid;   // < 48*128
        int j = idx >> 7, c = idx & 127;
        WoutT[idx] = (j < NCLASS) ? (_Float16)Wout[c * NCLASS + j] : (_Float16)0.f;
    }
}

__global__ __launch_bounds__(256) void k_bsum(const int* __restrict__ cnt, int* __restrict__ bsum) {
    int t = threadIdx.x, b = blockIdx.x;
    int i = b * 256 + t;
    int c = (i < NNODES) ? cnt[i] : 0;
    int v = c;
    v += __shfl_xor(v, 1);  v += __shfl_xor(v, 2);  v += __shfl_xor(v, 4);
    v += __shfl_xor(v, 8);  v += __shfl_xor(v, 16); v += __shfl_xor(v, 32);
    __shared__ int ws[4];
    if ((t & 63) == 0) ws[t >> 6] = v;
    __syncthreads();
    if (t == 0) bsum[b] = ws[0] + ws[1] + ws[2] + ws[3];
}

__global__ __launch_bounds__(256) void k_offsets(const int* __restrict__ cnt, const int* __restrict__ bsum,
                                                 int* __restrict__ offsets, float* __restrict__ dinv) {
    int t = threadIdx.x, b = blockIdx.x;
    int i = b * 256 + t;
    int c = (i < NNODES) ? cnt[i] : 0;
    int pv = (t < b) ? bsum[t] : 0;   // b <= 195 < 256
    int rv = pv;
    rv += __shfl_xor(rv, 1);  rv += __shfl_xor(rv, 2);  rv += __shfl_xor(rv, 4);
    rv += __shfl_xor(rv, 8);  rv += __shfl_xor(rv, 16); rv += __shfl_xor(rv, 32);
    __shared__ int wsum[4];
    __shared__ int part[256];
    if ((t & 63) == 0) wsum[t >> 6] = rv;
    part[t] = c;
    __syncthreads();
    int boff = wsum[0] + wsum[1] + wsum[2] + wsum[3];
#pragma unroll
    for (int d = 1; d < 256; d <<= 1) {
        int v = (t >= d) ? part[t - d] : 0;
        __syncthreads();
        part[t] += v;
        __syncthreads();
    }
    if (i < NNODES) {
        offsets[i] = boff + part[t] - c;
        dinv[i] = rsqrtf((float)c + 1.0f);
    }
    if (b == 0 && t == 0) offsets[NNODES] = NEDGES;
}

// ---------------- shared GEMM body: C[64,128] tile = (A @ W) * dinv; W staged in LDS ----------------
// smem serves as W-tile (34.8 KB) during MFMA, then is REUSED as the fp32 Cs epilogue buffer.
template <bool F32A>
__device__ __forceinline__ void gemm_body(const void* __restrict__ Av, const _Float16* __restrict__ WT,
                                          const float* __restrict__ dinv, _Float16* __restrict__ C,
                                          int m0, char* smem) {
    _Float16* Wsh = (_Float16*)smem;
    float (*Cs)[132] = (float (*)[132])smem;
    int tid = threadIdx.x;
    int wave = tid >> 6, lane = tid & 63;
    int quad = lane >> 4, l15 = lane & 15;
    int ko = quad * 8;

    stage_weight(WT, Wsh, tid);
    __syncthreads();

    floatx4 acc[4][2];
#pragma unroll
    for (int rt = 0; rt < 4; ++rt)
#pragma unroll
        for (int ct = 0; ct < 2; ++ct) acc[rt][ct] = (floatx4){0.f, 0.f, 0.f, 0.f};

#pragma unroll
    for (int kk = 0; kk < 4; ++kk) {
        half8 a[4], b[2];
#pragma unroll
        for (int rt = 0; rt < 4; ++rt) {
            int row = m0 + rt * 16 + l15;
            if (row > NNODES - 1) row = NNODES - 1;
            if (F32A) {
                const float* Ap = (const float*)Av + (size_t)row * 128 + kk * 32 + ko;
                float4 f0 = *(const float4*)Ap;
                float4 f1 = *(const float4*)(Ap + 4);
                a[rt] = (half8){(_Float16)f0.x, (_Float16)f0.y, (_Float16)f0.z, (_Float16)f0.w,
                                (_Float16)f1.x, (_Float16)f1.y, (_Float16)f1.z, (_Float16)f1.w};
            } else {
                a[rt] = *(const half8*)((const _Float16*)Av + (size_t)row * 128 + kk * 32 + ko);
            }
        }
#pragma unroll
        for (int ct = 0; ct < 2; ++ct) {
            int n = wave * 32 + ct * 16 + l15;
            b[ct] = *(const half8*)&Wsh[n * WSTRIDE + kk * 32 + ko];
        }
#pragma unroll
        for (int rt = 0; rt < 4; ++rt)
#pragma unroll
            for (int ct = 0; ct < 2; ++ct)
                acc[rt][ct] = __builtin_amdgcn_mfma_f32_16x16x32_f16(a[rt], b[ct], acc[rt][ct], 0, 0, 0);
    }
    __syncthreads();   // all waves done reading Wsh before Cs overwrites it

#pragma unroll
    for (int rt = 0; rt < 4; ++rt)
#pragma unroll
        for (int ct = 0; ct < 2; ++ct)
#pragma unroll
            for (int r = 0; r < 4; ++r)
                Cs[rt * 16 + quad * 4 + r][wave * 32 + ct * 16 + l15] = acc[rt][ct][r];
    __syncthreads();
    int row = tid >> 2, seg = tid & 3;
    int gm = m0 + row;
    if (gm < NNODES) {
        float sc = dinv[gm];
#pragma unroll
        for (int j = 0; j < 4; ++j) {
            float4 f0 = *(const float4*)&Cs[row][seg * 32 + j * 8];
            float4 f1 = *(const float4*)&Cs[row][seg * 32 + j * 8 + 4];
            half8 o = {(_Float16)(f0.x * sc), (_Float16)(f0.y * sc), (_Float16)(f0.z * sc), (_Float16)(f0.w * sc),
                       (_Float16)(f1.x * sc), (_Float16)(f1.y * sc), (_Float16)(f1.z * sc), (_Float16)(f1.w * sc)};
            *(half8*)(C + (size_t)gm * 128 + seg * 32 + j * 8) = o;
        }
    }
}

// ---------------- attention body: 128 nodes/block for ONE layer slab; Wsh from smem ----------------
__device__ __forceinline__ void attn_body(const _Float16* __restrict__ hs, const _Float16* __restrict__ WTatt,
                                          const float* __restrict__ a_att, float* __restrict__ scores,
                                          int layer, int abid, char* smem) {
    _Float16* Wsh = (_Float16*)smem;
    int tid = threadIdx.x;
    int wave = tid >> 6, lane = tid & 63;
    int quad = lane >> 4, l15 = lane & 15;
    int ko = quad * 8;
    int nb = abid * 128 + wave * 32;              // 32 nodes per wave

    stage_weight(WTatt, Wsh, tid);

    half8 af[2][4];                                // 2 row-tiles of 16 nodes
#pragma unroll
    for (int rt = 0; rt < 2; ++rt) {
        int node = nb + rt * 16 + l15;
        if (node > NNODES - 1) node = NNODES - 1;
        const _Float16* Ap = hs + (size_t)node * 128 + ko;
#pragma unroll
        for (int kk = 0; kk < 4; ++kk) af[rt][kk] = *(const half8*)(Ap + kk * 32);
    }
    __syncthreads();

    float p[2][4];
#pragma unroll
    for (int rt = 0; rt < 2; ++rt)
#pragma unroll
        for (int r = 0; r < 4; ++r) p[rt][r] = 0.f;
#pragma unroll
    for (int ct = 0; ct < 8; ++ct) {
        int ncol = ct * 16 + l15;
        half8 b[4];
#pragma unroll
        for (int kk = 0; kk < 4; ++kk) b[kk] = *(const half8*)&Wsh[ncol * WSTRIDE + kk * 32 + ko];
        floatx4 acc[2];
#pragma unroll
        for (int rt = 0; rt < 2; ++rt) acc[rt] = (floatx4){0.f, 0.f, 0.f, 0.f};
#pragma unroll
        for (int kk = 0; kk < 4; ++kk)
#pragma unroll
            for (int rt = 0; rt < 2; ++rt)
                acc[rt] = __builtin_amdgcn_mfma_f32_16x16x32_f16(af[rt][kk], b[kk], acc[rt], 0, 0, 0);
        float av = a_att[ncol];
#pragma unroll
        for (int rt = 0; rt < 2; ++rt)
#pragma unroll
            for (int r = 0; r < 4; ++r) p[rt][r] += av * fast_tanh(acc[rt][r]);
    }
#pragma unroll
    for (int rt = 0; rt < 2; ++rt)
#pragma unroll
        for (int r = 0; r < 4; ++r) {
            float v = p[rt][r];
            v += __shfl_xor(v, 1); v += __shfl_xor(v, 2);
            v += __shfl_xor(v, 4); v += __shfl_xor(v, 8);
            if (l15 == 0) {
                int nd = nb + rt * 16 + quad * 4 + r;
                if (nd < NNODES) scores[(size_t)nd * 4 + layer] = v;
            }
        }
}

// ---------------- fused: GEMM layer l | attn on layer l-1 (both read-only on hh[l-1]) ----------------
__global__ __launch_bounds__(256) void k_gemmattn(const _Float16* __restrict__ A, const _Float16* __restrict__ WT,
                                                  const float* __restrict__ dinv, _Float16* __restrict__ C,
                                                  const _Float16* __restrict__ WTatt, const float* __restrict__ a_att,
                                                  float* __restrict__ scores, int layer) {
    __shared__ __align__(16) char smem[SMEM_BYTES];
    int bid = blockIdx.x;
    if (bid < GEMMB) {
        gemm_body<false>(A, WT, dinv, C, bid * 64, smem);
    } else {
        attn_body(A, WTatt, a_att, scores, layer, bid - GEMMB, smem);
    }
}

// ---------------- standalone attn for the final layer ----------------
__global__ __launch_bounds__(256) void k_attn1(const _Float16* __restrict__ hs, const _Float16* __restrict__ WTatt,
                                               const float* __restrict__ a_att, float* __restrict__ scores,
                                               int layer) {
    __shared__ __align__(16) char smem[SMEM_BYTES];
    attn_body(hs, WTatt, a_att, scores, layer, blockIdx.x, smem);
}

// ---------------- fused: CSR fill (no atomic) | layer-0 GEMM straight from fp32 x ----------------
__global__ __launch_bounds__(256) void k_fillgemm(const int* __restrict__ src, const int* __restrict__ dst,
                                                  const int* __restrict__ offsets, const int* __restrict__ rank,
                                                  int* __restrict__ esrc,
                                                  const float* __restrict__ x, const _Float16* __restrict__ WT,
                                                  const float* __restrict__ dinv, _Float16* __restrict__ C) {
    __shared__ __align__(16) char smem[SMEM_BYTES];
    int bid = blockIdx.x;
    if (bid < GEMMB) {
        gemm_body<true>(x, WT, dinv, C, bid * 64, smem);
    } else {
        int e = (bid - GEMMB) * 256 + threadIdx.x;
        int d = dst[e];
        esrc[offsets[d] + rank[e]] = src[e];
    }
}

// ---------------- edge aggregation: quarter-wave rows, fully predicated 8-wide gather windows ----------
__global__ __launch_bounds__(256) void k_aggregate(const _Float16* __restrict__ hWs, const int* __restrict__ offsets,
                                                   const int* __restrict__ esrc, const float* __restrict__ dinv,
                                                   const float* __restrict__ bias, _Float16* __restrict__ outh) {
    __shared__ float bsh[128];
    int tid = threadIdx.x;
    if (tid < 128) bsh[tid] = bias[tid];
    __syncthreads();
    int lane = tid & 63, wave = tid >> 6;
    int half = lane >> 5;
    int q = (lane >> 4) & 1;
    int l16 = lane & 15;
    int c8 = l16 * 8;
    int n = blockIdx.x * 8 + wave * 2 + half;
    int beg = offsets[n], end = offsets[n + 1];
    float a0 = 0.f, a1 = 0.f, a2 = 0.f, a3 = 0.f, a4 = 0.f, a5 = 0.f, a6 = 0.f, a7 = 0.f;
    for (int e = beg + q; e < end; e += 16) {
        int  idx[8];
        float msk[8];
#pragma unroll
        for (int i = 0; i < 8; ++i) {
            int ei = e + 2 * i;
            int t = esrc[ei];            // esrc padded: speculative load in-bounds
            bool ok = ei < end;
            idx[i] = ok ? t : n;
            msk[i] = ok ? 1.f : 0.f;
        }
        half8 v[8];
#pragma unroll
        for (int i = 0; i < 8; ++i) v[i] = *(const half8*)(hWs + (size_t)idx[i] * 128 + c8);
#pragma unroll
        for (int i = 0; i < 8; ++i) {
            a0 += msk[i] * (float)v[i][0]; a1 += msk[i] * (float)v[i][1];
            a2 += msk[i] * (float)v[i][2]; a3 += msk[i] * (float)v[i][3];
            a4 += msk[i] * (float)v[i][4]; a5 += msk[i] * (float)v[i][5];
            a6 += msk[i] * (float)v[i][6]; a7 += msk[i] * (float)v[i][7];
        }
    }
    a0 += __shfl_xor(a0, 16); a1 += __shfl_xor(a1, 16); a2 += __shfl_xor(a2, 16); a3 += __shfl_xor(a3, 16);
    a4 += __shfl_xor(a4, 16); a5 += __shfl_xor(a5, 16); a6 += __shfl_xor(a6, 16); a7 += __shfl_xor(a7, 16);
    if (q == 0) {
        float dn = dinv[n];
        half8 sv = *(const half8*)(hWs + (size_t)n * 128 + c8);
        float4 b0 = *(const float4*)&bsh[c8];
        float4 b1 = *(const float4*)&bsh[c8 + 4];
        float r0 = (a0 + (float)sv[0]) * dn + b0.x;
        float r1 = (a1 + (float)sv[1]) * dn + b0.y;
        float r2 = (a2 + (float)sv[2]) * dn + b0.z;
        float r3 = (a3 + (float)sv[3]) * dn + b0.w;
        float r4 = (a4 + (float)sv[4]) * dn + b1.x;
        float r5 = (a5 + (float)sv[5]) * dn + b1.y;
        float r6 = (a6 + (float)sv[6]) * dn + b1.z;
        float r7 = (a7 + (float)sv[7]) * dn + b1.w;
        half8 o = {(_Float16)fmaxf(r0, 0.f), (_Float16)fmaxf(r1, 0.f),
                   (_Float16)fmaxf(r2, 0.f), (_Float16)fmaxf(r3, 0.f),
                   (_Float16)fmaxf(r4, 0.f), (_Float16)fmaxf(r5, 0.f),
                   (_Float16)fmaxf(r6, 0.f), (_Float16)fmaxf(r7, 0.f)};
        *(half8*)(outh + (size_t)n * 128 + c8) = o;
    }
}

// ---------------- softmax + layer-fuse (coalesced, all lanes) + MFMA out-projection ----------------
__global__ __launch_bounds__(256) void k_fuse_out(const _Float16* __restrict__ hbase, const float* __restrict__ scores,
                                                  const _Float16* __restrict__ WoutT, const float* __restrict__ bout,
                                                  float* __restrict__ out) {
    __shared__ __align__(16) _Float16 Fs[64][136];   // 17,408 B
    __shared__ float salpha[256];
    const size_t LSTR = (size_t)NNODES * 128;
    int tid = threadIdx.x;
    int n0 = blockIdx.x * 64;

    if (tid < 64) {
        int node = n0 + tid; if (node > NNODES - 1) node = NNODES - 1;
        float4 s = *(const float4*)(scores + (size_t)node * 4);
        float mx = fmaxf(fmaxf(s.x, s.y), fmaxf(s.z, s.w));
        float e0 = __expf(s.x - mx), e1 = __expf(s.y - mx), e2 = __expf(s.z - mx), e3 = __expf(s.w - mx);
        float inv = 1.0f / (e0 + e1 + e2 + e3);
        salpha[tid * 4 + 0] = e0 * inv; salpha[tid * 4 + 1] = e1 * inv;
        salpha[tid * 4 + 2] = e2 * inv; salpha[tid * 4 + 3] = e3 * inv;
    }
    __syncthreads();

    // fused = sum_l alpha_l * h_l; all 256 lanes, coalesced per (layer, j)
    {
        int no = tid >> 2, seg = tid & 3;
        int node = n0 + no; if (node > NNODES - 1) node = NNODES - 1;
        float al0 = salpha[no * 4 + 0], al1 = salpha[no * 4 + 1];
        float al2 = salpha[no * 4 + 2], al3 = salpha[no * 4 + 3];
        const _Float16* hp = hbase + (size_t)node * 128 + seg * 32;
#pragma unroll
        for (int j = 0; j < 4; ++j) {
            half8 h0 = *(const half8*)(hp + 0 * LSTR + j * 8);
            half8 h1 = *(const half8*)(hp + 1 * LSTR + j * 8);
            half8 h2 = *(const half8*)(hp + 2 * LSTR + j * 8);
            half8 h3 = *(const half8*)(hp + 3 * LSTR + j * 8);
            half8 f;
#pragma unroll
            for (int u = 0; u < 8; ++u)
                f[u] = (_Float16)(al0 * (float)h0[u] + al1 * (float)h1[u] +
                                  al2 * (float)h2[u] + al3 * (float)h3[u]);
            *(half8*)&Fs[no][seg * 32 + j * 8] = f;
        }
    }
    __syncthreads();

    // out-projection MFMA: 48 padded cols, masked fp32 write + bias
    int wave = tid >> 6, lane = tid & 63;
    int quad = lane >> 4, l15 = lane & 15;
    int ko = quad * 8;
    half8 ff[4];
    int frow = wave * 16 + l15;
#pragma unroll
    for (int kk = 0; kk < 4; ++kk) ff[kk] = *(const half8*)&Fs[frow][kk * 32 + ko];
#pragma unroll
    for (int ct = 0; ct < 3; ++ct) {
        const _Float16* Bp = WoutT + (ct * 16 + l15) * 128 + ko;
        half8 bw[4];
#pragma unroll
        for (int kk = 0; kk < 4; ++kk) bw[kk] = *(const half8*)(Bp + kk * 32);
        floatx4 acc = (floatx4){0.f, 0.f, 0.f, 0.f};
#pragma unroll
        for (int kk = 0; kk < 4; ++kk)
            acc = __builtin_amdgcn_mfma_f32_16x16x32_f16(ff[kk], bw[kk], acc, 0, 0, 0);
        int col = ct * 16 + l15;
        if (col < NCLASS) {
            float bv = bout[col];
#pragma unroll
            for (int r = 0; r < 4; ++r) {
                int node = n0 + wave * 16 + quad * 4 + r;
                if (node < NNODES) out[(size_t)node * NCLASS + col] = acc[r] + bv;
            }
        }
    }
}

extern "C" void kernel_launch(void* const* d_in, const int* in_sizes, int n_in,
                              void* d_out, int out_size, void* d_ws, size_t ws_size,
                              hipStream_t stream) {
    const float* x     = (const float*)d_in[0];
    const int*   ei    = (const int*)d_in[1];
    const float* convW = (const float*)d_in[2];
    const float* convb = (const float*)d_in[3];
    const float* W_att = (const float*)d_in[4];
    const float* a_att = (const float*)d_in[5];
    const float* W_out = (const float*)d_in[6];
    const float* b_out = (const float*)d_in[7];
    float* out = (float*)d_out;

    char* ws = (char*)d_ws;
    size_t off = 0;
    auto take = [&](size_t nbytes) { char* p = ws + off; off += (nbytes + 255) & ~(size_t)255; return p; };
    float*     dinv    = (float*)take(NNODES * 4);
    int*       cnt     = (int*)take(NNODES * 4);
    int*       rank    = (int*)take(NEDGES * 4);
    int*       offsets = (int*)take((NNODES + 1) * 4);
    int*       bsum    = (int*)take(256 * 4);
    int*       esrc    = (int*)take(NEDGES * 4 + 256);   // +64 ints pad for speculative loads
    _Float16*  WoutT   = (_Float16*)take((size_t)48 * 128 * 2);
    float*     scores  = (float*)take(NNODES * 4 * 4);
    _Float16*  WT      = (_Float16*)take((size_t)5 * 128 * 128 * 2);
    _Float16*  hWs     = (_Float16*)take((size_t)NNODES * 128 * 2);
    _Float16*  hh[4];
    for (int l = 0; l < 4; ++l) hh[l] = (_Float16*)take((size_t)NNODES * 128 * 2);
    // NOTE: hh slabs are 12,800,000 B each (multiple of 256) -> contiguous; k_fuse_out relies on it.

    const int* src = ei;
    const int* dst = ei + NEDGES;

    hipMemsetAsync(cnt, 0, NNODES * 4, stream);
    k_pre<<<CNTB + PREPB + WOUTB, 256, 0, stream>>>(dst, cnt, rank, convW, W_att, WT, W_out, WoutT);
    k_bsum<<<NBLK_SCAN, 256, 0, stream>>>(cnt, bsum);
    k_offsets<<<NBLK_SCAN, 256, 0, stream>>>(cnt, bsum, offsets, dinv);
    k_fillgemm<<<GEMMB + CNTB, 256, 0, stream>>>(src, dst, offsets, rank, esrc, x, WT, dinv, hWs);

    k_aggregate<<<NNODES / 8, 256, 0, stream>>>(hWs, offsets, esrc, dinv, convb + 0 * 128, hh[0]);
    for (int l = 1; l < 4; ++l) {
        // gemm layer l fused with attention scores for layer l-1 (both only read hh[l-1])
        k_gemmattn<<<GEMMB + ATTN1B, 256, 0, stream>>>(hh[l - 1], WT + l * 16384, dinv, hWs,
                                                       WT + 4 * 16384, a_att, scores, l - 1);
        k_aggregate<<<NNODES / 8, 256, 0, stream>>>(hWs, offsets, esrc, dinv, convb + l * 128, hh[l]);
    }
    k_attn1<<<ATTN1B, 256, 0, stream>>>(hh[3], WT + 4 * 16384, a_att, scores, 3);
    k_fuse_out<<<GEMMB, 256, 0, stream>>>(hh[0], scores, WoutT, b_out, out);
}